// Round 4
// baseline (190.888 us; speedup 1.0000x reference)
//
#include <hip/hip_runtime.h>
#include <stdint.h>

// Problem constants
#define S_LEN   2048
#define BATCH   2
#define DM      1024
#define NHEADS  16
#define HD      64
#define WIN     256
#define MROWS   (BATCH * S_LEN)          // 4096
#define NX      (MROWS * DM)             // 4194304 x elements
#define NW      (DM * DM)                // 1048576 per weight

typedef unsigned short u16;
typedef unsigned int   u32;

using short8  = __attribute__((ext_vector_type(8))) short;   // 8 bf16 (4 VGPRs)
using floatx4 = __attribute__((ext_vector_type(4))) float;   // MFMA acc

__device__ __forceinline__ float bf2f(u16 u) {
    union { u32 u; float f; } v; v.u = ((u32)u) << 16; return v.f;
}
__device__ __forceinline__ u16 f2bf(float f) {
    union { float f; u32 u; } v; v.f = f;
    u32 u = v.u;
    u += 0x7fffu + ((u >> 16) & 1u);   // RNE
    return (u16)(u >> 16);
}

// async global->LDS, 16B per lane. LDS dest = wave-uniform base + lane*16.
__device__ __forceinline__ void load_lds16(const void* g, void* l) {
    __builtin_amdgcn_global_load_lds(
        (__attribute__((address_space(1))) void*)(uintptr_t)g,
        (__attribute__((address_space(3))) void*)(unsigned int)(uintptr_t)l,
        16, 0, 0);
}

// ---------------------------------------------------------------------------
// Dtype probe: flag = 0 -> bf16 inputs ; flag = 1 -> fp32 inputs
// ---------------------------------------------------------------------------
__global__ __launch_bounds__(256) void detect_mode(const u16* x, int* flag) {
    __shared__ int sbad;
    int t = threadIdx.x;
    if (t == 0) sbad = 0;
    __syncthreads();
    int bad = 0;
    for (int i = t; i < 4096; i += 256) {
        float v = bf2f(x[i]);
        if (!(fabsf(v) < 1e6f)) bad = 1;
    }
    if (bad) atomicOr(&sbad, 1);
    __syncthreads();
    if (t == 0) flag[0] = sbad;
}

// ---------------------------------------------------------------------------
// fp32-mode only: convert inputs to bf16 (bf16 mode: early exit).
// ---------------------------------------------------------------------------
__global__ __launch_bounds__(256) void normalize_inputs(
        const void* x, const void* wq, const void* wk, const void* wv, const void* wo,
        u16* xb, u16* wcat, u16* wob, const int* flag) {
    if (flag[0] == 0) return;
    const int total = NX + 4 * NW;
    for (int i = blockIdx.x * blockDim.x + threadIdx.x; i < total;
         i += gridDim.x * blockDim.x) {
        const void* src; u16* dst; int li;
        if (i < NX)              { src = x;  dst = xb;            li = i; }
        else if (i < NX + NW)    { src = wq; dst = wcat;          li = i - NX; }
        else if (i < NX + 2*NW)  { src = wk; dst = wcat + NW;     li = i - NX - NW; }
        else if (i < NX + 3*NW)  { src = wv; dst = wcat + 2*NW;   li = i - NX - 2*NW; }
        else                     { src = wo; dst = wob;           li = i - NX - 3*NW; }
        dst[li] = f2bf(((const float*)src)[li]);
    }
}

// ---------------------------------------------------------------------------
// m97-style GEMM  C[M,N] = A[M,K] * B[N,K]^T  (bf16 in, fp32 acc)
// 128x128 tile, BK=32, 256 threads (4 waves, 4x4 16x16x32 frags each).
// LDS [128][32] unpadded (global_load_lds lane order) with XOR segment
// swizzle: LDS[row][s] holds global segment s ^ (row&3) ^ ((row>>2)&1).
// Per-lane GLOBAL address carries the swizzle; read-back XORs it out.
// Kills the stride-64B 8-way ds_read_b128 bank conflict (banks now 2-way).
// final_out==0: bf16 out, and columns < 1024 (Q) pre-scaled by 0.125
// (exact in bf16) so attention skips the score scale.
// ---------------------------------------------------------------------------
#define BM 128
#define BN 128
#define BK 32

__global__ __launch_bounds__(256) void gemm_lds(
        const u16* __restrict__ Araw, const u16* __restrict__ Anorm,
        const u16* __restrict__ B0, const u16* __restrict__ B1,
        const u16* __restrict__ B2, const u16* __restrict__ Bnorm,
        void* __restrict__ C, int M, int N, int K,
        const int* __restrict__ flag, int final_out) {
    __shared__ __align__(16) u16 sA[BM * BK];   // 8 KB
    __shared__ __align__(16) u16 sB[BN * BK];   // 8 KB

    const int mode = flag[0];
    const int tid  = threadIdx.x;
    const int lane = tid & 63, wave = tid >> 6;
    const int m0  = blockIdx.x * BM;
    const int n0g = blockIdx.y * BN;
    const int third = n0g >> 10;                 // which weight (1024-col thirds)
    const u16* A = mode ? Anorm : Araw;
    const u16* B = mode ? (Bnorm + (size_t)third * NW)
                        : (third == 0 ? B0 : (third == 1 ? B1 : B2));
    const int n0 = n0g - third * 1024;           // row within selected weight

    // staging: wave w, issue r covers rows r*64 + w*16 .. +15 (16 rows x 64B)
    const int srow = lane >> 2;                  // row within 16-row group
    const int fsw  = ((lane >> 2) & 3) ^ ((lane >> 4) & 1);   // swizzle(row)
    const int scol = ((lane & 3) ^ fsw) * 8;     // swizzled global segment
    const u16* gA = A + (size_t)(m0 + wave * 16 + srow) * K + scol;
    const u16* gB = B + (size_t)(n0 + wave * 16 + srow) * K + scol;
    u16* lA = sA + wave * 16 * BK;               // wave-uniform LDS base
    u16* lB = sB + wave * 16 * BK;
    const size_t rstep = (size_t)64 * K;

    const int n16 = lane & 15, quad = lane >> 4;
    const int m_off = (wave >> 1) * 64, n_off = (wave & 1) * 64;
    // frag rows are m_off/n_off + i*16 + n16 -> row bits 0..2 == n16 bits 0..2
    const int fr   = (n16 & 3) ^ ((n16 >> 2) & 1);
    const int cswz = ((quad ^ fr) & 3) * 8;      // swizzled LDS column

    floatx4 acc[4][4] = {};

    for (int k0 = 0; k0 < K; k0 += BK) {
        load_lds16(gA + k0,         lA);
        load_lds16(gA + k0 + rstep, lA + 64 * BK);
        load_lds16(gB + k0,         lB);
        load_lds16(gB + k0 + rstep, lB + 64 * BK);
        __syncthreads();   // drains vmcnt: staged data visible to all waves
        short8 af[4], bfr[4];
        #pragma unroll
        for (int i = 0; i < 4; ++i)
            af[i] = *(const short8*)&sA[(m_off + i * 16 + n16) * BK + cswz];
        #pragma unroll
        for (int j = 0; j < 4; ++j)
            bfr[j] = *(const short8*)&sB[(n_off + j * 16 + n16) * BK + cswz];
        #pragma unroll
        for (int i = 0; i < 4; ++i) {
            #pragma unroll
            for (int j = 0; j < 4; ++j)
                acc[i][j] = __builtin_amdgcn_mfma_f32_16x16x32_bf16(
                    af[i], bfr[j], acc[i][j], 0, 0, 0);
        }
        __syncthreads();   // all reads done before next overwrite
    }

    // C/D layout: col = lane&15, row = quad*4 + reg
    const int outmode = final_out ? mode : 0;
    const float oscale = (!final_out && n0g < 1024) ? 0.125f : 1.0f;
    #pragma unroll
    for (int i = 0; i < 4; ++i) {
        #pragma unroll
        for (int j = 0; j < 4; ++j) {
            #pragma unroll
            for (int r = 0; r < 4; ++r) {
                int row = m0 + m_off + i * 16 + quad * 4 + r;
                int col = n0g + n_off + j * 16 + n16;
                size_t idx = (size_t)row * N + col;
                float v = acc[i][j][r] * oscale;
                if (outmode) ((float*)C)[idx] = v;
                else         ((u16*)C)[idx]   = f2bf(v);
            }
        }
    }
}

// ---------------------------------------------------------------------------
// MFMA flash-style sliding-window attention.
// Block = 512 threads = 8 waves = 128 queries of one (b,h).
// Q pre-scaled by 0.125 in the QKV GEMM epilogue.
// VPAD=394: b128 V reads stride 197 words (mod 32 = 5) -> 2-way = free.
// ---------------------------------------------------------------------------
#define KSTG 384
#define KPAD 72
#define VPAD 394

__global__ __launch_bounds__(512) void attn_mfma(
        const u16* __restrict__ QKV, u16* __restrict__ O) {
    __shared__ __align__(16) u16 sK[KSTG][KPAD];     // 55.3 KB
    __shared__ __align__(16) u16 sVt[64][VPAD];      // 50.4 KB
    __shared__ __align__(16) u16 sP[8][2][16][40];   // 20.5 KB

    const int bh = blockIdx.x;
    const int b  = bh >> 4, h = bh & 15;
    const int q0 = blockIdx.y * 128;
    const int kb0 = q0 - (WIN - 1);
    const int tid = threadIdx.x;
    const u16* base = QKV + (size_t)b * S_LEN * 3072;

    for (int i = tid; i < KSTG * 8; i += 512) {
        int row = i >> 3, seg = i & 7;
        int kg = kb0 + row;
        uint4 kv = {0u, 0u, 0u, 0u}, vv = {0u, 0u, 0u, 0u};
        if (kg >= 0 && kg < S_LEN) {
            const u16* rp = base + (size_t)kg * 3072 + h * 64 + seg * 8;
            kv = *(const uint4*)(rp + 1024);
            vv = *(const uint4*)(rp + 2048);
        }
        *(uint4*)&sK[row][seg * 8] = kv;
        const u16* vp = (const u16*)&vv;
        #pragma unroll
        for (int t2 = 0; t2 < 8; ++t2) sVt[seg * 8 + t2][row] = vp[t2];
    }
    __syncthreads();

    const int wave = tid >> 6, lane = tid & 63;
    const int n16 = lane & 15, quad = lane >> 4;
    const int sqb = q0 + wave * 16;
    const int sq_r0 = sqb + quad * 4;

    const u16* qrow = base + (size_t)(sqb + n16) * 3072 + h * 64;
    short8 aq0 = *(const short8*)(qrow + quad * 8);
    short8 aq1 = *(const short8*)(qrow + 32 + quad * 8);

    floatx4 o0 = {0.f,0.f,0.f,0.f}, o1 = o0, o2 = o0, o3 = o0;
    float m[4] = {-1e30f, -1e30f, -1e30f, -1e30f};
    float l[4] = {0.f, 0.f, 0.f, 0.f};
    const int c0 = wave >> 1;

    for (int cc = 0; cc < 9; ++cc) {
        const int krel = (c0 + cc) * 32;
        short8 bk00 = *(const short8*)&sK[krel + n16][quad * 8];
        short8 bk01 = *(const short8*)&sK[krel + n16][32 + quad * 8];
        short8 bk10 = *(const short8*)&sK[krel + 16 + n16][quad * 8];
        short8 bk11 = *(const short8*)&sK[krel + 16 + n16][32 + quad * 8];
        floatx4 z = {0.f, 0.f, 0.f, 0.f};
        floatx4 s0 = __builtin_amdgcn_mfma_f32_16x16x32_bf16(aq0, bk00, z, 0, 0, 0);
        s0 = __builtin_amdgcn_mfma_f32_16x16x32_bf16(aq1, bk01, s0, 0, 0, 0);
        floatx4 s1 = __builtin_amdgcn_mfma_f32_16x16x32_bf16(aq0, bk10, z, 0, 0, 0);
        s1 = __builtin_amdgcn_mfma_f32_16x16x32_bf16(aq1, bk11, s1, 0, 0, 0);

        const int kg0 = kb0 + krel + n16;
        const int kg1 = kg0 + 16;
        float alpha[4], p0[4], p1[4];
        #pragma unroll
        for (int r = 0; r < 4; ++r) {
            int sq = sq_r0 + r;
            int lo = sq - (WIN - 1); if (lo < 0) lo = 0;
            float v0 = (kg0 >= lo && kg0 <= sq) ? s0[r] : -1e30f;
            float v1 = (kg1 >= lo && kg1 <= sq) ? s1[r] : -1e30f;
            float mc = fmaxf(v0, v1);
            mc = fmaxf(mc, __shfl_xor(mc, 1));
            mc = fmaxf(mc, __shfl_xor(mc, 2));
            mc = fmaxf(mc, __shfl_xor(mc, 4));
            mc = fmaxf(mc, __shfl_xor(mc, 8));
            float mn = fmaxf(m[r], mc);
            alpha[r] = __expf(m[r] - mn);
            m[r] = mn;
            p0[r] = __expf(v0 - mn);
            p1[r] = __expf(v1 - mn);
            float rs = p0[r] + p1[r];
            rs += __shfl_xor(rs, 1);
            rs += __shfl_xor(rs, 2);
            rs += __shfl_xor(rs, 4);
            rs += __shfl_xor(rs, 8);
            l[r] = l[r] * alpha[r] + rs;
        }
        #pragma unroll
        for (int r = 0; r < 4; ++r) {
            o0[r] *= alpha[r]; o1[r] *= alpha[r];
            o2[r] *= alpha[r]; o3[r] *= alpha[r];
        }
        u16* pw = &sP[wave][cc & 1][0][0];
        #pragma unroll
        for (int r = 0; r < 4; ++r) {
            pw[(quad * 4 + r) * 40 + n16]      = f2bf(p0[r]);
            pw[(quad * 4 + r) * 40 + 16 + n16] = f2bf(p1[r]);
        }
        asm volatile("s_waitcnt lgkmcnt(0)" ::: "memory");
        short8 pa  = *(const short8*)&pw[n16 * 40 + quad * 8];
        short8 bv0 = *(const short8*)&sVt[n16]     [krel + quad * 8];
        short8 bv1 = *(const short8*)&sVt[16 + n16][krel + quad * 8];
        short8 bv2 = *(const short8*)&sVt[32 + n16][krel + quad * 8];
        short8 bv3 = *(const short8*)&sVt[48 + n16][krel + quad * 8];
        o0 = __builtin_amdgcn_mfma_f32_16x16x32_bf16(pa, bv0, o0, 0, 0, 0);
        o1 = __builtin_amdgcn_mfma_f32_16x16x32_bf16(pa, bv1, o1, 0, 0, 0);
        o2 = __builtin_amdgcn_mfma_f32_16x16x32_bf16(pa, bv2, o2, 0, 0, 0);
        o3 = __builtin_amdgcn_mfma_f32_16x16x32_bf16(pa, bv3, o3, 0, 0, 0);
    }

    #pragma unroll
    for (int r = 0; r < 4; ++r) {
        float rl = 1.0f / l[r];
        size_t ro = ((size_t)(b * S_LEN + sq_r0 + r)) * DM + h * 64 + n16;
        O[ro]      = f2bf(o0[r] * rl);
        O[ro + 16] = f2bf(o1[r] * rl);
        O[ro + 32] = f2bf(o2[r] * rl);
        O[ro + 48] = f2bf(o3[r] * rl);
    }
}

// ---------------------------------------------------------------------------
extern "C" void kernel_launch(void* const* d_in, const int* in_sizes, int n_in,
                              void* d_out, int out_size, void* d_ws, size_t ws_size,
                              hipStream_t stream) {
    char* ws = (char*)d_ws;
    int* flag = (int*)ws;
    u16* xb   = (u16*)(ws + 1024);
    u16* wcat = xb   + (size_t)NX;
    u16* wob  = wcat + (size_t)3 * NW;
    u16* qkv  = wob  + (size_t)NW;
    u16* ob   = qkv  + (size_t)MROWS * 3 * DM;

    const u16* xr  = (const u16*)d_in[0];
    const u16* wqr = (const u16*)d_in[1];
    const u16* wkr = (const u16*)d_in[2];
    const u16* wvr = (const u16*)d_in[3];
    const u16* wor = (const u16*)d_in[4];

    detect_mode<<<1, 256, 0, stream>>>(xr, flag);
    normalize_inputs<<<4096, 256, 0, stream>>>(
        d_in[0], d_in[1], d_in[2], d_in[3], d_in[4], xb, wcat, wob, flag);
    // QKV = x * Wcat^T : [4096,1024] x [3072,1024]^T -> [4096,3072]
    gemm_lds<<<dim3(MROWS / BM, 3072 / BN), 256, 0, stream>>>(
        xr, xb, wqr, wkr, wvr, wcat, qkv, MROWS, 3 * DM, DM, flag, 0);
    // attention -> ob [4096,1024]
    attn_mfma<<<dim3(BATCH * NHEADS, S_LEN / 128), 512, 0, stream>>>(qkv, ob);
    // out = ob * Wo^T -> d_out [4096,1024]
    gemm_lds<<<dim3(MROWS / BM, DM / BN), 256, 0, stream>>>(
        ob, ob, wor, wor, wor, wob, d_out, MROWS, DM, DM, flag, 1);
}

// Round 5
// 173.871 us; speedup vs baseline: 1.0979x; 1.0979x over previous
//
#include <hip/hip_runtime.h>
#include <stdint.h>

// Problem constants
#define S_LEN   2048
#define BATCH   2
#define DM      1024
#define NHEADS  16
#define HD      64
#define WIN     256
#define MROWS   (BATCH * S_LEN)          // 4096
#define NX      (MROWS * DM)             // 4194304 x elements
#define NW      (DM * DM)                // 1048576 per weight

typedef unsigned short u16;
typedef unsigned int   u32;

using short8  = __attribute__((ext_vector_type(8))) short;   // 8 bf16 (4 VGPRs)
using floatx4 = __attribute__((ext_vector_type(4))) float;   // MFMA acc

__device__ __forceinline__ float bf2f(u16 u) {
    union { u32 u; float f; } v; v.u = ((u32)u) << 16; return v.f;
}
__device__ __forceinline__ u16 f2bf(float f) {
    union { float f; u32 u; } v; v.f = f;
    u32 u = v.u;
    u += 0x7fffu + ((u >> 16) & 1u);   // RNE
    return (u16)(u >> 16);
}

// async global->LDS, 16B per lane. LDS dest = wave-uniform base + lane*16.
__device__ __forceinline__ void load_lds16(const void* g, void* l) {
    __builtin_amdgcn_global_load_lds(
        (__attribute__((address_space(1))) void*)(uintptr_t)g,
        (__attribute__((address_space(3))) void*)(unsigned int)(uintptr_t)l,
        16, 0, 0);
}

// ---------------------------------------------------------------------------
// Dtype probe: flag = 0 -> bf16 inputs ; flag = 1 -> fp32 inputs
// ---------------------------------------------------------------------------
__global__ __launch_bounds__(256) void detect_mode(const u16* x, int* flag) {
    __shared__ int sbad;
    int t = threadIdx.x;
    if (t == 0) sbad = 0;
    __syncthreads();
    int bad = 0;
    for (int i = t; i < 4096; i += 256) {
        float v = bf2f(x[i]);
        if (!(fabsf(v) < 1e6f)) bad = 1;
    }
    if (bad) atomicOr(&sbad, 1);
    __syncthreads();
    if (t == 0) flag[0] = sbad;
}

// ---------------------------------------------------------------------------
// fp32-mode only: convert inputs to bf16 (bf16 mode: early exit).
// ---------------------------------------------------------------------------
__global__ __launch_bounds__(256) void normalize_inputs(
        const void* x, const void* wq, const void* wk, const void* wv, const void* wo,
        u16* xb, u16* wcat, u16* wob, const int* flag) {
    if (flag[0] == 0) return;
    const int total = NX + 4 * NW;
    for (int i = blockIdx.x * blockDim.x + threadIdx.x; i < total;
         i += gridDim.x * blockDim.x) {
        const void* src; u16* dst; int li;
        if (i < NX)              { src = x;  dst = xb;            li = i; }
        else if (i < NX + NW)    { src = wq; dst = wcat;          li = i - NX; }
        else if (i < NX + 2*NW)  { src = wk; dst = wcat + NW;     li = i - NX - NW; }
        else if (i < NX + 3*NW)  { src = wv; dst = wcat + 2*NW;   li = i - NX - 2*NW; }
        else                     { src = wo; dst = wob;           li = i - NX - 3*NW; }
        dst[li] = f2bf(((const float*)src)[li]);
    }
}

// ---------------------------------------------------------------------------
// Pipelined GEMM  C[M,N] = A[M,K] * B[N,K]^T  (bf16 in, fp32 acc)
// 128xTBN tile, BK=32, 256 threads (4 waves). Double-buffered LDS with ONE
// __syncthreads per iter: its implicit vmcnt(0) waits the current buffer's
// global_load_lds AND fences prev compute; prefetch for iter+1 is issued
// right after, so it flies during the whole compute phase.
// SQ_LDS_BANK_CONFLICT ~4 cyc per ds_read_b128 here is intrinsic phase
// serialization (R3 lesson) — banks are already uniform; don't chase it.
// final_out==0: bf16 out, cols<1024 (Q) pre-scaled by 0.125 for attention.
// ---------------------------------------------------------------------------
#define BM 128
#define BK 32

template<int TBN>
__global__ __launch_bounds__(256) void gemm_lds(
        const u16* __restrict__ Araw, const u16* __restrict__ Anorm,
        const u16* __restrict__ B0, const u16* __restrict__ B1,
        const u16* __restrict__ B2, const u16* __restrict__ Bnorm,
        void* __restrict__ C, int M, int N, int K,
        const int* __restrict__ flag, int final_out) {
    constexpr int NF = TBN / 32;                 // B frags per wave
    __shared__ __align__(16) u16 sA[2][BM * BK];
    __shared__ __align__(16) u16 sB[2][TBN * BK];

    const int mode = flag[0];
    const int tid  = threadIdx.x;
    const int lane = tid & 63, wave = tid >> 6;
    const int m0  = blockIdx.x * BM;
    const int n0g = blockIdx.y * TBN;
    const int third = n0g >> 10;                 // which weight (1024-col thirds)
    const u16* A = mode ? Anorm : Araw;
    const u16* B = mode ? (Bnorm + (size_t)third * NW)
                        : (third == 0 ? B0 : (third == 1 ? B1 : B2));
    const int n0 = n0g - third * 1024;           // row within selected weight

    // staging: wave w, issue r covers rows r*64 + w*16 .. +15 (16 rows x 64B)
    const int srow = lane >> 2;                  // row within 16-row group
    const int scol = (lane & 3) * 8;             // element col within BK
    const u16* gA = A + (size_t)(m0 + wave * 16 + srow) * K + scol;
    const u16* gB = B + (size_t)(n0 + wave * 16 + srow) * K + scol;
    const size_t rstep = (size_t)64 * K;
    const int lofs = wave * 16 * BK;             // wave-uniform LDS base offset

    const int n16 = lane & 15, quad = lane >> 4;
    const int m_off = (wave >> 1) * 64, n_off = (wave & 1) * (TBN / 2);

    floatx4 acc[4][NF] = {};
    const int NIT = K / BK;

    auto issue = [&](int k0, int buf) {
        u16* lA = sA[buf] + lofs;
        u16* lB = sB[buf] + lofs;
        load_lds16(gA + k0,         lA);
        load_lds16(gA + k0 + rstep, lA + 64 * BK);
        load_lds16(gB + k0, lB);
        if (TBN == 128) load_lds16(gB + k0 + rstep, lB + 64 * BK);
    };

    issue(0, 0);
    for (int it = 0; it < NIT; ++it) {
        const int cur = it & 1;
        __syncthreads();   // vmcnt(0): buf[cur] staged; also fences prev compute
        if (it + 1 < NIT) issue((it + 1) * BK, 1 - cur);
        short8 af[4], bfr[NF];
        #pragma unroll
        for (int i = 0; i < 4; ++i)
            af[i] = *(const short8*)&sA[cur][(m_off + i * 16 + n16) * BK + quad * 8];
        #pragma unroll
        for (int j = 0; j < NF; ++j)
            bfr[j] = *(const short8*)&sB[cur][(n_off + j * 16 + n16) * BK + quad * 8];
        #pragma unroll
        for (int i = 0; i < 4; ++i) {
            #pragma unroll
            for (int j = 0; j < NF; ++j)
                acc[i][j] = __builtin_amdgcn_mfma_f32_16x16x32_bf16(
                    af[i], bfr[j], acc[i][j], 0, 0, 0);
        }
    }

    // C/D layout: col = lane&15, row = quad*4 + reg
    const int outmode = final_out ? mode : 0;
    const float oscale = (!final_out && n0g < 1024) ? 0.125f : 1.0f;
    #pragma unroll
    for (int i = 0; i < 4; ++i) {
        #pragma unroll
        for (int j = 0; j < NF; ++j) {
            #pragma unroll
            for (int r = 0; r < 4; ++r) {
                int row = m0 + m_off + i * 16 + quad * 4 + r;
                int col = n0g + n_off + j * 16 + n16;
                size_t idx = (size_t)row * N + col;
                float v = acc[i][j][r] * oscale;
                if (outmode) ((float*)C)[idx] = v;
                else         ((u16*)C)[idx]   = f2bf(v);
            }
        }
    }
}

// ---------------------------------------------------------------------------
// MFMA flash-style sliding-window attention (unchanged).
// Block = 512 threads = 8 waves = 128 queries of one (b,h).
// Q pre-scaled by 0.125 in the QKV GEMM epilogue.
// ---------------------------------------------------------------------------
#define KSTG 384
#define KPAD 72
#define VPAD 394

__global__ __launch_bounds__(512) void attn_mfma(
        const u16* __restrict__ QKV, u16* __restrict__ O) {
    __shared__ __align__(16) u16 sK[KSTG][KPAD];     // 55.3 KB
    __shared__ __align__(16) u16 sVt[64][VPAD];      // 50.4 KB
    __shared__ __align__(16) u16 sP[8][2][16][40];   // 20.5 KB

    const int bh = blockIdx.x;
    const int b  = bh >> 4, h = bh & 15;
    const int q0 = blockIdx.y * 128;
    const int kb0 = q0 - (WIN - 1);
    const int tid = threadIdx.x;
    const u16* base = QKV + (size_t)b * S_LEN * 3072;

    for (int i = tid; i < KSTG * 8; i += 512) {
        int row = i >> 3, seg = i & 7;
        int kg = kb0 + row;
        uint4 kv = {0u, 0u, 0u, 0u}, vv = {0u, 0u, 0u, 0u};
        if (kg >= 0 && kg < S_LEN) {
            const u16* rp = base + (size_t)kg * 3072 + h * 64 + seg * 8;
            kv = *(const uint4*)(rp + 1024);
            vv = *(const uint4*)(rp + 2048);
        }
        *(uint4*)&sK[row][seg * 8] = kv;
        const u16* vp = (const u16*)&vv;
        #pragma unroll
        for (int t2 = 0; t2 < 8; ++t2) sVt[seg * 8 + t2][row] = vp[t2];
    }
    __syncthreads();

    const int wave = tid >> 6, lane = tid & 63;
    const int n16 = lane & 15, quad = lane >> 4;
    const int sqb = q0 + wave * 16;
    const int sq_r0 = sqb + quad * 4;

    const u16* qrow = base + (size_t)(sqb + n16) * 3072 + h * 64;
    short8 aq0 = *(const short8*)(qrow + quad * 8);
    short8 aq1 = *(const short8*)(qrow + 32 + quad * 8);

    floatx4 o0 = {0.f,0.f,0.f,0.f}, o1 = o0, o2 = o0, o3 = o0;
    float m[4] = {-1e30f, -1e30f, -1e30f, -1e30f};
    float l[4] = {0.f, 0.f, 0.f, 0.f};
    const int c0 = wave >> 1;

    for (int cc = 0; cc < 9; ++cc) {
        const int krel = (c0 + cc) * 32;
        short8 bk00 = *(const short8*)&sK[krel + n16][quad * 8];
        short8 bk01 = *(const short8*)&sK[krel + n16][32 + quad * 8];
        short8 bk10 = *(const short8*)&sK[krel + 16 + n16][quad * 8];
        short8 bk11 = *(const short8*)&sK[krel + 16 + n16][32 + quad * 8];
        floatx4 z = {0.f, 0.f, 0.f, 0.f};
        floatx4 s0 = __builtin_amdgcn_mfma_f32_16x16x32_bf16(aq0, bk00, z, 0, 0, 0);
        s0 = __builtin_amdgcn_mfma_f32_16x16x32_bf16(aq1, bk01, s0, 0, 0, 0);
        floatx4 s1 = __builtin_amdgcn_mfma_f32_16x16x32_bf16(aq0, bk10, z, 0, 0, 0);
        s1 = __builtin_amdgcn_mfma_f32_16x16x32_bf16(aq1, bk11, s1, 0, 0, 0);

        const int kg0 = kb0 + krel + n16;
        const int kg1 = kg0 + 16;
        float alpha[4], p0[4], p1[4];
        #pragma unroll
        for (int r = 0; r < 4; ++r) {
            int sq = sq_r0 + r;
            int lo = sq - (WIN - 1); if (lo < 0) lo = 0;
            float v0 = (kg0 >= lo && kg0 <= sq) ? s0[r] : -1e30f;
            float v1 = (kg1 >= lo && kg1 <= sq) ? s1[r] : -1e30f;
            float mc = fmaxf(v0, v1);
            mc = fmaxf(mc, __shfl_xor(mc, 1));
            mc = fmaxf(mc, __shfl_xor(mc, 2));
            mc = fmaxf(mc, __shfl_xor(mc, 4));
            mc = fmaxf(mc, __shfl_xor(mc, 8));
            float mn = fmaxf(m[r], mc);
            alpha[r] = __expf(m[r] - mn);
            m[r] = mn;
            p0[r] = __expf(v0 - mn);
            p1[r] = __expf(v1 - mn);
            float rs = p0[r] + p1[r];
            rs += __shfl_xor(rs, 1);
            rs += __shfl_xor(rs, 2);
            rs += __shfl_xor(rs, 4);
            rs += __shfl_xor(rs, 8);
            l[r] = l[r] * alpha[r] + rs;
        }
        #pragma unroll
        for (int r = 0; r < 4; ++r) {
            o0[r] *= alpha[r]; o1[r] *= alpha[r];
            o2[r] *= alpha[r]; o3[r] *= alpha[r];
        }
        u16* pw = &sP[wave][cc & 1][0][0];
        #pragma unroll
        for (int r = 0; r < 4; ++r) {
            pw[(quad * 4 + r) * 40 + n16]      = f2bf(p0[r]);
            pw[(quad * 4 + r) * 40 + 16 + n16] = f2bf(p1[r]);
        }
        asm volatile("s_waitcnt lgkmcnt(0)" ::: "memory");
        short8 pa  = *(const short8*)&pw[n16 * 40 + quad * 8];
        short8 bv0 = *(const short8*)&sVt[n16]     [krel + quad * 8];
        short8 bv1 = *(const short8*)&sVt[16 + n16][krel + quad * 8];
        short8 bv2 = *(const short8*)&sVt[32 + n16][krel + quad * 8];
        short8 bv3 = *(const short8*)&sVt[48 + n16][krel + quad * 8];
        o0 = __builtin_amdgcn_mfma_f32_16x16x32_bf16(pa, bv0, o0, 0, 0, 0);
        o1 = __builtin_amdgcn_mfma_f32_16x16x32_bf16(pa, bv1, o1, 0, 0, 0);
        o2 = __builtin_amdgcn_mfma_f32_16x16x32_bf16(pa, bv2, o2, 0, 0, 0);
        o3 = __builtin_amdgcn_mfma_f32_16x16x32_bf16(pa, bv3, o3, 0, 0, 0);
    }

    #pragma unroll
    for (int r = 0; r < 4; ++r) {
        float rl = 1.0f / l[r];
        size_t ro = ((size_t)(b * S_LEN + sq_r0 + r)) * DM + h * 64 + n16;
        O[ro]      = f2bf(o0[r] * rl);
        O[ro + 16] = f2bf(o1[r] * rl);
        O[ro + 32] = f2bf(o2[r] * rl);
        O[ro + 48] = f2bf(o3[r] * rl);
    }
}

// ---------------------------------------------------------------------------
extern "C" void kernel_launch(void* const* d_in, const int* in_sizes, int n_in,
                              void* d_out, int out_size, void* d_ws, size_t ws_size,
                              hipStream_t stream) {
    char* ws = (char*)d_ws;
    int* flag = (int*)ws;
    u16* xb   = (u16*)(ws + 1024);
    u16* wcat = xb   + (size_t)NX;
    u16* wob  = wcat + (size_t)3 * NW;
    u16* qkv  = wob  + (size_t)NW;
    u16* ob   = qkv  + (size_t)MROWS * 3 * DM;

    const u16* xr  = (const u16*)d_in[0];
    const u16* wqr = (const u16*)d_in[1];
    const u16* wkr = (const u16*)d_in[2];
    const u16* wvr = (const u16*)d_in[3];
    const u16* wor = (const u16*)d_in[4];

    detect_mode<<<1, 256, 0, stream>>>(xr, flag);
    normalize_inputs<<<1024, 256, 0, stream>>>(
        d_in[0], d_in[1], d_in[2], d_in[3], d_in[4], xb, wcat, wob, flag);
    // QKV = x * Wcat^T : [4096,1024] x [3072,1024]^T -> [4096,3072]
    gemm_lds<128><<<dim3(MROWS / BM, 3072 / 128), 256, 0, stream>>>(
        xr, xb, wqr, wkr, wvr, wcat, qkv, MROWS, 3 * DM, DM, flag, 0);
    // attention -> ob [4096,1024]
    attn_mfma<<<dim3(BATCH * NHEADS, S_LEN / 128), 512, 0, stream>>>(qkv, ob);
    // out = ob * Wo^T -> d_out [4096,1024]  (BN=64: 512 blocks = 2/CU)
    gemm_lds<64><<<dim3(MROWS / BM, DM / 64), 256, 0, stream>>>(
        ob, ob, wor, wor, wor, wob, d_out, MROWS, DM, DM, flag, 1);
}